// Round 17
// baseline (91.755 us; speedup 1.0000x reference)
//
#include <hip/hip_runtime.h>
#include <hip/hip_bf16.h>
#include <math.h>

#define N_ITEMS 2900000
#define BDIM 4096
#define DDIM 768
#define CSPLIT 4751424   // gemm copies u < CSPLIT; tail copies the rest (exact)

typedef float f32x4 __attribute__((ext_vector_type(4)));
typedef __bf16 bf16x8 __attribute__((ext_vector_type(8)));

__device__ inline unsigned short f2bf(float f) {
    unsigned int u = __float_as_uint(f);
    unsigned int lsb = (u >> 16) & 1u;
    u += 0x7fffu + lsb;
    return (unsigned short)(u >> 16);
}

__device__ inline void gload16(const void* g, void* l) {
    __builtin_amdgcn_global_load_lds(
        (const __attribute__((address_space(1))) void*)g,
        (__attribute__((address_space(3))) void*)l, 16, 0, 0);
}

// ---------------- prep: single-pass convert + diag dot + tau gathers -------
__global__ __launch_bounds__(256) void prep_kernel(
        const float* __restrict__ img, const float* __restrict__ txt,
        const int* __restrict__ image_ids, const int* __restrict__ text_ids,
        const float* __restrict__ tau_I, const float* __restrict__ tau_T,
        unsigned short* __restrict__ Xbf, unsigned short* __restrict__ Ybf,
        float* __restrict__ diag, float* __restrict__ tau_row,
        float* __restrict__ out) {
    const int w = blockIdx.x * 4 + (threadIdx.x >> 6);
    const int lane = threadIdx.x & 63;
    const float4* ia = (const float4*)(img + (size_t)w * DDIM);
    const float4* tb = (const float4*)(txt + (size_t)w * DDIM);
    ushort4* xa = (ushort4*)(Xbf + (size_t)w * DDIM);
    ushort4* yb = (ushort4*)(Ybf + (size_t)w * DDIM);
    float s = 0.f;
    #pragma unroll
    for (int j = 0; j < 3; j++) {                 // 192 float4/row = 64 lanes x 3
        const int idx = lane + j * 64;
        const float4 a = ia[idx], b = tb[idx];
        ushort4 oa, ob;
        oa.x = f2bf(a.x); oa.y = f2bf(a.y); oa.z = f2bf(a.z); oa.w = f2bf(a.w);
        ob.x = f2bf(b.x); ob.y = f2bf(b.y); ob.z = f2bf(b.z); ob.w = f2bf(b.w);
        xa[idx] = oa; yb[idx] = ob;
        s += a.x * b.x + a.y * b.y + a.z * b.z + a.w * b.w;
    }
    #pragma unroll
    for (int d = 32; d >= 1; d >>= 1) s += __shfl_xor(s, d);
    if (lane == 0) diag[w] = s;
    if (lane == 1) {
        float t0 = tau_I[image_ids[w]];
        tau_row[w] = t0;
        out[1 + w] = t0;          // output 1: tau_image
    }
    if (lane == 2) {
        float t0 = tau_T[text_ids[w]];
        tau_row[BDIM + w] = t0;
        out[1 + BDIM + w] = t0;   // output 2: tau_text
    }
}

// ---------------- 256^2-tile 8-wave dbuf MFMA GEMM + interleaved copy ------
// (r13 structure; copy range reduced to u < CSPLIT — overflow slots read a
//  fixed L2-resident address and store to dump, keeping vmcnt(20) valid.)
__global__ __launch_bounds__(512) void gemm_kernel(
        const unsigned short* __restrict__ Xbf, const unsigned short* __restrict__ Ybf,
        const float* __restrict__ diag, const float* __restrict__ tau_row,
        float* __restrict__ partials /* [2][4096][64][3] */,
        const float* s0, const float* s1, const float* s2, const float* s3,
        const float* s4, const float* s5, const float* s6, const float* s7,
        float* __restrict__ cdst /* out + 8193 */, float* __restrict__ dump) {
    __shared__ unsigned short As[2][16384];   // [buf][256 rows][64 k] = 32KB each
    __shared__ unsigned short Bs[2][16384];

    const int cb = blockIdx.x, rb = blockIdx.y;
    const int t = threadIdx.x;
    const int wave = t >> 6, lane = t & 63;
    const int wr = wave >> 2, wc = wave & 3;
    const int g = lane >> 4, r16 = lane & 15;

    f32x4 acc[8][4];
    #pragma unroll
    for (int m = 0; m < 8; m++)
        #pragma unroll
        for (int n = 0; n < 4; n++)
            #pragma unroll
            for (int q = 0; q < 4; q++) acc[m][n][q] = 0.f;

    const int srow = t >> 3;                       // 0..63
    const int sgr  = (t & 7) ^ (srow & 7);
    const unsigned short* pA[4];
    const unsigned short* pB[4];
    #pragma unroll
    for (int i = 0; i < 4; i++) {
        pA[i] = Xbf + (size_t)(rb * 256 + i * 64 + srow) * DDIM + sgr * 8;
        pB[i] = Ybf + (size_t)(cb * 256 + i * 64 + srow) * DDIM + sgr * 8;
    }

    #define STAGE(buf, kk) do {                                                   \
        const size_t ko_ = (size_t)(kk) * 64;                                     \
        _Pragma("unroll")                                                         \
        for (int i_ = 0; i_ < 4; i_++) {                                          \
            gload16(pA[i_] + ko_, (char*)As + (buf)*32768 + i_*8192 + wave*1024); \
            gload16(pB[i_] + ko_, (char*)Bs + (buf)*32768 + i_*8192 + wave*1024); \
        }                                                                         \
    } while (0)

    const int gtid = (rb * 16 + cb) * 512 + t;
    f32x4 cval[4];
    int cu_[4];
    auto srcp = [&](int k) -> const float* {
        switch (k) {
            case 0: return s0; case 1: return s1; case 2: return s2; case 3: return s3;
            case 4: return s4; case 5: return s5; case 6: return s6; default: return s7;
        }
    };
    auto CLOAD = [&](int slot, int c) {
        const int u = c * 131072 + gtid;
        cu_[slot] = u;
        const int k = u / 725000;                   // u<CSPLIT -> k<=6
        const int i = u - k * 725000;
        // overflow: fixed L2-resident address (single line, ~free fetch)
        const f32x4* addr = (u < CSPLIT) ? ((const f32x4*)srcp(k) + i)
                                         : (const f32x4*)s7;
        cval[slot] = __builtin_nontemporal_load(addr);
    };
    auto CSTORE = [&](int slot) {
        const int u = cu_[slot];
        const int k = u / 725000;
        const int i = u - k * 725000;
        float* real = cdst + (size_t)(k < 8 ? k : 0) * N_ITEMS + (size_t)(k < 8 ? i : 0) * 4;
        float* dd = (u < CSPLIT) ? real : (dump + ((t & 127) << 2));  // cndmask select
        dd[0] = cval[slot][0];
        dd[1] = cval[slot][1];
        dd[2] = cval[slot][2];
        dd[3] = cval[slot][3];
    };

    STAGE(0, 0);
    #pragma unroll
    for (int j = 0; j < 4; j++) CLOAD(j, j);
    asm volatile("s_waitcnt vmcnt(4)" ::: "memory");   // tile-0 stage landed
    __builtin_amdgcn_s_barrier();

    for (int kk = 0; kk < 12; ++kk) {
        const int cur = kk & 1;
        if (kk < 11) STAGE(cur ^ 1, kk + 1);          // 8 VMEM
        #pragma unroll
        for (int j = 0; j < 4; j++) {                 // 16 + 4 VMEM
            CSTORE(j);
            if (kk < 11) CLOAD(j, (kk + 1) * 4 + j);
        }
        const char* Ac = (const char*)As + cur * 32768;
        const char* Bc = (const char*)Bs + cur * 32768;
        #pragma unroll
        for (int ks = 0; ks < 2; ++ks) {
            bf16x8 af[8], bfr[4];
            #pragma unroll
            for (int m = 0; m < 8; m++) {
                const int row = wr * 128 + m * 16 + r16;
                const int gr = (ks * 4 + g) ^ (r16 & 7);
                af[m] = *(const bf16x8*)(Ac + row * 128 + gr * 16);
            }
            #pragma unroll
            for (int n = 0; n < 4; n++) {
                const int row = wc * 64 + n * 16 + r16;
                const int gr = (ks * 4 + g) ^ (r16 & 7);
                bfr[n] = *(const bf16x8*)(Bc + row * 128 + gr * 16);
            }
            #pragma unroll
            for (int m = 0; m < 8; m++)
                #pragma unroll
                for (int n = 0; n < 4; n++)
                    acc[m][n] = __builtin_amdgcn_mfma_f32_16x16x32_bf16(af[m], bfr[n], acc[m][n], 0, 0, 0);
        }
        if (kk < 11) {
            asm volatile("s_waitcnt vmcnt(20)" ::: "memory");
            __builtin_amdgcn_s_barrier();
        }
    }
    #undef STAGE

    const int R0 = rb * 256 + wr * 128;
    const int C0 = cb * 256 + wc * 64;

    // ---- row side (image)
    #pragma unroll
    for (int m = 0; m < 8; m++) {
        #pragma unroll
        for (int q = 0; q < 4; q++) {
            const int rowg = R0 + m * 16 + g * 4 + q;
            const float dgv = diag[rowg];
            const float itau = 1.0f / tau_row[rowg];
            float x4[4];
            float mloc = -3.0e38f;
            #pragma unroll
            for (int n = 0; n < 4; n++) {
                const int colg = C0 + n * 16 + r16;
                const float x = (acc[m][n][q] - dgv) * itau;
                x4[n] = x;
                mloc = (colg != rowg) ? fmaxf(mloc, x) : mloc;
            }
            #pragma unroll
            for (int d = 1; d < 16; d <<= 1) mloc = fmaxf(mloc, __shfl_xor(mloc, d));
            float E = 0.f, F = 0.f;
            #pragma unroll
            for (int n = 0; n < 4; n++) {
                const int colg = C0 + n * 16 + r16;
                const float e = (colg != rowg) ? __expf(x4[n] - mloc) : 0.f;
                E += e; F += e * x4[n];
            }
            #pragma unroll
            for (int d = 1; d < 16; d <<= 1) {
                E += __shfl_xor(E, d);
                F += __shfl_xor(F, d);
            }
            if (r16 == 0) {
                const int chunk = cb * 4 + wc;       // 64 col-chunks of 64
                float* pp = partials + (((size_t)rowg) * 64 + chunk) * 3;
                pp[0] = mloc; pp[1] = E; pp[2] = F;
            }
        }
    }

    // ---- col side (text)
    #pragma unroll
    for (int n = 0; n < 4; n++) {
        const int colg = C0 + n * 16 + r16;
        const float dgc = diag[colg];
        const float itc = 1.0f / tau_row[BDIM + colg];
        float mloc = -3.0e38f;
        #pragma unroll
        for (int m = 0; m < 8; m++)
            #pragma unroll
            for (int q = 0; q < 4; q++) {
                const int rowg = R0 + m * 16 + g * 4 + q;
                const float x = (acc[m][n][q] - dgc) * itc;
                mloc = (rowg != colg) ? fmaxf(mloc, x) : mloc;
            }
        mloc = fmaxf(mloc, __shfl_xor(mloc, 16));
        mloc = fmaxf(mloc, __shfl_xor(mloc, 32));
        float E = 0.f, F = 0.f;
        #pragma unroll
        for (int m = 0; m < 8; m++)
            #pragma unroll
            for (int q = 0; q < 4; q++) {
                const int rowg = R0 + m * 16 + g * 4 + q;
                const float x = (acc[m][n][q] - dgc) * itc;
                const float e = (rowg != colg) ? __expf(x - mloc) : 0.f;
                E += e; F += e * x;
            }
        E += __shfl_xor(E, 16); F += __shfl_xor(F, 16);
        E += __shfl_xor(E, 32); F += __shfl_xor(F, 32);
        if (g == 0) {
            const int rchunk = rb * 2 + wr;          // 32 row-chunks of 128
            float* pp = partials + (((size_t)BDIM + colg) * 64 + rchunk) * 3;
            pp[0] = mloc; pp[1] = E; pp[2] = F;
        }
    }
}

// ---------------- tail: combine + scalar math + dedup scatter + copy slice -
// 1024 blocks x 512 threads (8 rows/block, halves sids staging). Also copies
// the state slice [CSPLIT, 5.8M) — tau_I tail + tau_T — 2 f32x4/thread:
// loads issued FIRST (hide under staging + dup-scan), stores at the end.
// Tail's HBM was 0.7% busy; this traffic is nearly free.
__global__ __launch_bounds__(512) void tail_kernel(
        const float* __restrict__ partials,
        const int* __restrict__ image_ids, const int* __restrict__ text_ids,
        const float* __restrict__ b_I, const float* __restrict__ b_T,
        const float* __restrict__ s_I, const float* __restrict__ s_T,
        const float* __restrict__ u_I, const float* __restrict__ u_T,
        const float* __restrict__ tau_I, const float* __restrict__ tau_T,
        const float* __restrict__ tau_row, const int* __restrict__ epoch_ptr,
        float* __restrict__ loss_arr, float* __restrict__ cdst /* out+8193 */,
        float* __restrict__ out) {
    __shared__ int sids[BDIM];
    const int bx = blockIdx.x;
    const int p = bx >> 9;                      // 512 blocks per side
    const int* ids = p ? text_ids : image_ids;

    // ---- copy slice: issue loads first (u in [CSPLIT, 5800000), k in {6,7})
    const int ctid = bx * 512 + threadIdx.x;    // 0..524287
    const int u0 = CSPLIT + ctid;
    const int u1 = CSPLIT + 524288 + ctid;      // CSPLIT + 2*524288 == 5800000
    const int k0 = u0 / 725000, i0 = u0 - k0 * 725000;
    const int k1 = u1 / 725000, i1 = u1 - k1 * 725000;
    const f32x4 cv0 = __builtin_nontemporal_load(
        (const f32x4*)((k0 == 6 ? tau_I : tau_T)) + i0);
    const f32x4 cv1 = __builtin_nontemporal_load(
        (const f32x4*)((k1 == 6 ? tau_I : tau_T)) + i1);

    for (int i = threadIdx.x; i < BDIM / 4; i += 512)
        ((int4*)sids)[i] = ((const int4*)ids)[i];

    const int wave = threadIdx.x >> 6, lane = threadIdx.x & 63;
    const int row = (bx & 511) * 8 + wave;
    float m, E, F;
    if (p == 1 && lane >= 32) {
        m = -3.0e38f; E = 0.f; F = 0.f;
    } else {
        const float* pp = partials + (((size_t)p * BDIM + row) * 64 + lane) * 3;
        m = pp[0]; E = pp[1]; F = pp[2];
    }
    #pragma unroll
    for (int d = 1; d < 64; d <<= 1) {
        float mo = __shfl_xor(m, d), Eo = __shfl_xor(E, d), Fo = __shfl_xor(F, d);
        float mn = fmaxf(m, mo);
        float a1 = expf(m - mn), a2 = expf(mo - mn);
        E = E * a1 + Eo * a2;
        F = F * a1 + Fo * a2;
        m = mn;
    }
    const int id = ids[row];
    const float ob = p ? b_T[id] : b_I[id];
    const float so = p ? s_T[id] : s_I[id];
    const float uo = p ? u_T[id] : u_I[id];
    const float tv = tau_row[p * BDIM + row];
    const float m0 = fmaxf(ob, 0.0f);      // reference max includes idt[i,i]=0 and old_b
    if (m0 > m) { float sc = expf(m - m0); E *= sc; F *= sc; m = m0; }
    float sI = (*epoch_ptr == 0) ? E : 0.2f * so * expf(ob - m) + 0.8f * E;
    float sc_ = fmaxf(sI, 1e-14f);
    float ratio = F / sc_;
    float twi = logf(sc_ * (1.0f / 4095.0f)) + m + 8.0f - ratio;
    float uc = fminf(fmaxf(twi, -5.0f), 5.0f);
    float ub = 0.5f * uo + 0.5f * uc;
    float tb = fminf(fmaxf(tv - 0.03f * ub, 0.005f), 0.05f);
    if (lane == 0) loss_arr[p * BDIM + row] = tv * ratio;

    __syncthreads();                        // sids staged
    const int myid = sids[row];
    bool dup = false;
    for (int c = row + 1 + lane; c < BDIM; c += 64)
        dup |= (sids[c] == myid);
    if (!__any(dup) && lane < 4) {          // a later duplicate wins -> skip
        const float v = (lane == 0) ? m : (lane == 1) ? sI : (lane == 2) ? ub : tb;
        const int arr = (lane == 0) ? (2 + p) : (lane == 1) ? (0 + p)
                      : (lane == 2) ? (4 + p) : (6 + p);
        out[8193 + (size_t)arr * N_ITEMS + myid] = v;
    }

    // ---- copy slice: stores last (dst 4B-aligned only)
    {
        float* d0 = cdst + (size_t)k0 * N_ITEMS + (size_t)i0 * 4;
        d0[0] = cv0[0]; d0[1] = cv0[1]; d0[2] = cv0[2]; d0[3] = cv0[3];
        float* d1 = cdst + (size_t)k1 * N_ITEMS + (size_t)i1 * 4;
        d1[0] = cv1[0]; d1[1] = cv1[1]; d1[2] = cv1[2]; d1[3] = cv1[3];
    }
}

// ---------------- deterministic loss reduction -----------------------------
__global__ void loss_kernel(const float* __restrict__ loss_arr, float* __restrict__ out) {
    __shared__ float wsum[16];
    int t = threadIdx.x;
    float s = 0.f;
    for (int i = t; i < 2 * BDIM; i += 1024) s += loss_arr[i];
    #pragma unroll
    for (int d = 32; d >= 1; d >>= 1) s += __shfl_xor(s, d);
    if ((t & 63) == 0) wsum[t >> 6] = s;
    __syncthreads();
    if (t == 0) {
        float tot = 0.f;
        for (int i = 0; i < 16; i++) tot += wsum[i];
        out[0] = tot * (1.0f / (float)BDIM);  // mean(img)+mean(txt) = sum(all)/B
    }
}

extern "C" void kernel_launch(void* const* d_in, const int* in_sizes, int n_in,
                              void* d_out, int out_size, void* d_ws, size_t ws_size,
                              hipStream_t stream) {
    const float* img       = (const float*)d_in[0];
    const float* txt       = (const float*)d_in[1];
    const int*   image_ids = (const int*)d_in[2];
    const int*   text_ids  = (const int*)d_in[3];
    const int*   epoch     = (const int*)d_in[4];
    const float* s_I   = (const float*)d_in[6];
    const float* s_T   = (const float*)d_in[7];
    const float* b_I   = (const float*)d_in[8];
    const float* b_T   = (const float*)d_in[9];
    const float* u_I   = (const float*)d_in[10];
    const float* u_T   = (const float*)d_in[11];
    const float* tau_I = (const float*)d_in[12];
    const float* tau_T = (const float*)d_in[13];
    float* out = (float*)d_out;

    char* ws = (char*)d_ws;
    unsigned short* Xbf = (unsigned short*)ws;                    // 6,291,456 B
    unsigned short* Ybf = (unsigned short*)(ws + 6291456);        // 6,291,456 B
    float* diag     = (float*)(ws + 12582912);                    // 16 KB
    float* tau_row  = (float*)(ws + 12599296);                    // 32 KB
    float* partials = (float*)(ws + 12632064);                    // 6,291,456 B
    float* loss_arr = (float*)(ws + 18923520);                    // 32 KB
    float* dump     = (float*)(ws + 18956288);                    // 2 KB scratch

    prep_kernel<<<1024, 256, 0, stream>>>(img, txt, image_ids, text_ids, tau_I, tau_T,
                                          Xbf, Ybf, diag, tau_row, out);
    gemm_kernel<<<dim3(16, 16), 512, 0, stream>>>(Xbf, Ybf, diag, tau_row, partials,
                                                  s_I, s_T, b_I, b_T, u_I, u_T,
                                                  tau_I, tau_T, out + 8193, dump);
    tail_kernel<<<1024, 512, 0, stream>>>(partials, image_ids, text_ids,
                                          b_I, b_T, s_I, s_T, u_I, u_T,
                                          tau_I, tau_T, tau_row, epoch,
                                          loss_arr, out + 8193, out);
    loss_kernel<<<1, 1024, 0, stream>>>(loss_arr, out);
}

// Round 18
// 91.218 us; speedup vs baseline: 1.0059x; 1.0059x over previous
//
#include <hip/hip_runtime.h>
#include <hip/hip_bf16.h>
#include <math.h>

#define N_ITEMS 2900000
#define BDIM 4096
#define DDIM 768

typedef float f32x4 __attribute__((ext_vector_type(4)));
typedef __bf16 bf16x8 __attribute__((ext_vector_type(8)));

__device__ inline unsigned short f2bf(float f) {
    unsigned int u = __float_as_uint(f);
    unsigned int lsb = (u >> 16) & 1u;
    u += 0x7fffu + lsb;
    return (unsigned short)(u >> 16);
}

__device__ inline void gload16(const void* g, void* l) {
    __builtin_amdgcn_global_load_lds(
        (const __attribute__((address_space(1))) void*)g,
        (__attribute__((address_space(3))) void*)l, 16, 0, 0);
}

// ---------------- prep: single-pass convert + diag dot + tau gathers -------
// 1024 blocks x 4 waves; wave w handles row w of BOTH img and txt: loads each
// row once (3 float4/lane, coalesced), converts+stores bf16, accumulates the
// diag dot product in the same pass.
__global__ __launch_bounds__(256) void prep_kernel(
        const float* __restrict__ img, const float* __restrict__ txt,
        const int* __restrict__ image_ids, const int* __restrict__ text_ids,
        const float* __restrict__ tau_I, const float* __restrict__ tau_T,
        unsigned short* __restrict__ Xbf, unsigned short* __restrict__ Ybf,
        float* __restrict__ diag, float* __restrict__ tau_row,
        float* __restrict__ out) {
    const int w = blockIdx.x * 4 + (threadIdx.x >> 6);
    const int lane = threadIdx.x & 63;
    const float4* ia = (const float4*)(img + (size_t)w * DDIM);
    const float4* tb = (const float4*)(txt + (size_t)w * DDIM);
    ushort4* xa = (ushort4*)(Xbf + (size_t)w * DDIM);
    ushort4* yb = (ushort4*)(Ybf + (size_t)w * DDIM);
    float s = 0.f;
    #pragma unroll
    for (int j = 0; j < 3; j++) {                 // 192 float4/row = 64 lanes x 3
        const int idx = lane + j * 64;
        const float4 a = ia[idx], b = tb[idx];
        ushort4 oa, ob;
        oa.x = f2bf(a.x); oa.y = f2bf(a.y); oa.z = f2bf(a.z); oa.w = f2bf(a.w);
        ob.x = f2bf(b.x); ob.y = f2bf(b.y); ob.z = f2bf(b.z); ob.w = f2bf(b.w);
        xa[idx] = oa; yb[idx] = ob;
        s += a.x * b.x + a.y * b.y + a.z * b.z + a.w * b.w;
    }
    #pragma unroll
    for (int d = 32; d >= 1; d >>= 1) s += __shfl_xor(s, d);
    if (lane == 0) diag[w] = s;
    if (lane == 1) {
        float t0 = tau_I[image_ids[w]];
        tau_row[w] = t0;
        out[1 + w] = t0;          // output 1: tau_image
    }
    if (lane == 2) {
        float t0 = tau_T[text_ids[w]];
        tau_row[BDIM + w] = t0;
        out[1 + BDIM + w] = t0;   // output 2: tau_text
    }
}

// ---------------- 256^2-tile 8-wave dbuf MFMA GEMM + interleaved copy ------
// (best measured structure — 2-phase dbuf, XOR swizzle, counted vmcnt(20),
//  full state copy in 4 register slots, compiler-scheduled MFMA)
__global__ __launch_bounds__(512) void gemm_kernel(
        const unsigned short* __restrict__ Xbf, const unsigned short* __restrict__ Ybf,
        const float* __restrict__ diag, const float* __restrict__ tau_row,
        float* __restrict__ partials /* [2][4096][64][3] */,
        const float* s0, const float* s1, const float* s2, const float* s3,
        const float* s4, const float* s5, const float* s6, const float* s7,
        float* __restrict__ cdst /* out + 8193 */, float* __restrict__ dump) {
    __shared__ unsigned short As[2][16384];   // [buf][256 rows][64 k] = 32KB each
    __shared__ unsigned short Bs[2][16384];

    const int cb = blockIdx.x, rb = blockIdx.y;
    const int t = threadIdx.x;
    const int wave = t >> 6, lane = t & 63;
    const int wr = wave >> 2, wc = wave & 3;
    const int g = lane >> 4, r16 = lane & 15;

    f32x4 acc[8][4];
    #pragma unroll
    for (int m = 0; m < 8; m++)
        #pragma unroll
        for (int n = 0; n < 4; n++)
            #pragma unroll
            for (int q = 0; q < 4; q++) acc[m][n][q] = 0.f;

    const int srow = t >> 3;                       // 0..63
    const int sgr  = (t & 7) ^ (srow & 7);
    const unsigned short* pA[4];
    const unsigned short* pB[4];
    #pragma unroll
    for (int i = 0; i < 4; i++) {
        pA[i] = Xbf + (size_t)(rb * 256 + i * 64 + srow) * DDIM + sgr * 8;
        pB[i] = Ybf + (size_t)(cb * 256 + i * 64 + srow) * DDIM + sgr * 8;
    }

    #define STAGE(buf, kk) do {                                                   \
        const size_t ko_ = (size_t)(kk) * 64;                                     \
        _Pragma("unroll")                                                         \
        for (int i_ = 0; i_ < 4; i_++) {                                          \
            gload16(pA[i_] + ko_, (char*)As + (buf)*32768 + i_*8192 + wave*1024); \
            gload16(pB[i_] + ko_, (char*)Bs + (buf)*32768 + i_*8192 + wave*1024); \
        }                                                                         \
    } while (0)

    const int gtid = (rb * 16 + cb) * 512 + t;
    f32x4 cval[4];
    int cu_[4];
    auto srcp = [&](int k) -> const float* {
        switch (k) {
            case 0: return s0; case 1: return s1; case 2: return s2; case 3: return s3;
            case 4: return s4; case 5: return s5; case 6: return s6; default: return s7;
        }
    };
    auto CLOAD = [&](int slot, int c) {
        const int u = c * 131072 + gtid;
        cu_[slot] = u;
        const int k = u / 725000;                   // k<=8; clamp into s7
        const int i = u - k * 725000;
        cval[slot] = __builtin_nontemporal_load((const f32x4*)srcp(k < 8 ? k : 7) +
                                                (k < 8 ? i : (i % 725000)));
    };
    auto CSTORE = [&](int slot) {
        const int u = cu_[slot];
        const int k = u / 725000;
        const int i = u - k * 725000;
        float* real = cdst + (size_t)(k < 8 ? k : 0) * N_ITEMS + (size_t)(k < 8 ? i : 0) * 4;
        float* dd = (u < 5800000) ? real : (dump + ((t & 127) << 2));  // cndmask select
        dd[0] = cval[slot][0];
        dd[1] = cval[slot][1];
        dd[2] = cval[slot][2];
        dd[3] = cval[slot][3];
    };

    STAGE(0, 0);
    #pragma unroll
    for (int j = 0; j < 4; j++) CLOAD(j, j);
    asm volatile("s_waitcnt vmcnt(4)" ::: "memory");   // tile-0 stage landed
    __builtin_amdgcn_s_barrier();

    for (int kk = 0; kk < 12; ++kk) {
        const int cur = kk & 1;
        if (kk < 11) STAGE(cur ^ 1, kk + 1);          // 8 VMEM
        #pragma unroll
        for (int j = 0; j < 4; j++) {                 // 16 + 4 VMEM
            CSTORE(j);
            if (kk < 11) CLOAD(j, (kk + 1) * 4 + j);
        }
        const char* Ac = (const char*)As + cur * 32768;
        const char* Bc = (const char*)Bs + cur * 32768;
        #pragma unroll
        for (int ks = 0; ks < 2; ++ks) {
            bf16x8 af[8], bfr[4];
            #pragma unroll
            for (int m = 0; m < 8; m++) {
                const int row = wr * 128 + m * 16 + r16;
                const int gr = (ks * 4 + g) ^ (r16 & 7);
                af[m] = *(const bf16x8*)(Ac + row * 128 + gr * 16);
            }
            #pragma unroll
            for (int n = 0; n < 4; n++) {
                const int row = wc * 64 + n * 16 + r16;
                const int gr = (ks * 4 + g) ^ (r16 & 7);
                bfr[n] = *(const bf16x8*)(Bc + row * 128 + gr * 16);
            }
            #pragma unroll
            for (int m = 0; m < 8; m++)
                #pragma unroll
                for (int n = 0; n < 4; n++)
                    acc[m][n] = __builtin_amdgcn_mfma_f32_16x16x32_bf16(af[m], bfr[n], acc[m][n], 0, 0, 0);
        }
        if (kk < 11) {
            asm volatile("s_waitcnt vmcnt(20)" ::: "memory");
            __builtin_amdgcn_s_barrier();
        }
    }
    #undef STAGE

    const int R0 = rb * 256 + wr * 128;
    const int C0 = cb * 256 + wc * 64;

    // ---- row side (image)
    #pragma unroll
    for (int m = 0; m < 8; m++) {
        #pragma unroll
        for (int q = 0; q < 4; q++) {
            const int rowg = R0 + m * 16 + g * 4 + q;
            const float dgv = diag[rowg];
            const float itau = 1.0f / tau_row[rowg];
            float x4[4];
            float mloc = -3.0e38f;
            #pragma unroll
            for (int n = 0; n < 4; n++) {
                const int colg = C0 + n * 16 + r16;
                const float x = (acc[m][n][q] - dgv) * itau;
                x4[n] = x;
                mloc = (colg != rowg) ? fmaxf(mloc, x) : mloc;
            }
            #pragma unroll
            for (int d = 1; d < 16; d <<= 1) mloc = fmaxf(mloc, __shfl_xor(mloc, d));
            float E = 0.f, F = 0.f;
            #pragma unroll
            for (int n = 0; n < 4; n++) {
                const int colg = C0 + n * 16 + r16;
                const float e = (colg != rowg) ? __expf(x4[n] - mloc) : 0.f;
                E += e; F += e * x4[n];
            }
            #pragma unroll
            for (int d = 1; d < 16; d <<= 1) {
                E += __shfl_xor(E, d);
                F += __shfl_xor(F, d);
            }
            if (r16 == 0) {
                const int chunk = cb * 4 + wc;       // 64 col-chunks of 64
                float* pp = partials + (((size_t)rowg) * 64 + chunk) * 3;
                pp[0] = mloc; pp[1] = E; pp[2] = F;
            }
        }
    }

    // ---- col side (text)
    #pragma unroll
    for (int n = 0; n < 4; n++) {
        const int colg = C0 + n * 16 + r16;
        const float dgc = diag[colg];
        const float itc = 1.0f / tau_row[BDIM + colg];
        float mloc = -3.0e38f;
        #pragma unroll
        for (int m = 0; m < 8; m++)
            #pragma unroll
            for (int q = 0; q < 4; q++) {
                const int rowg = R0 + m * 16 + g * 4 + q;
                const float x = (acc[m][n][q] - dgc) * itc;
                mloc = (rowg != colg) ? fmaxf(mloc, x) : mloc;
            }
        mloc = fmaxf(mloc, __shfl_xor(mloc, 16));
        mloc = fmaxf(mloc, __shfl_xor(mloc, 32));
        float E = 0.f, F = 0.f;
        #pragma unroll
        for (int m = 0; m < 8; m++)
            #pragma unroll
            for (int q = 0; q < 4; q++) {
                const int rowg = R0 + m * 16 + g * 4 + q;
                const float x = (acc[m][n][q] - dgc) * itc;
                const float e = (rowg != colg) ? __expf(x - mloc) : 0.f;
                E += e; F += e * x;
            }
        E += __shfl_xor(E, 16); F += __shfl_xor(F, 16);
        E += __shfl_xor(E, 32); F += __shfl_xor(F, 32);
        if (g == 0) {
            const int rchunk = rb * 2 + wr;          // 32 row-chunks of 128
            float* pp = partials + (((size_t)BDIM + colg) * 64 + rchunk) * 3;
            pp[0] = mloc; pp[1] = E; pp[2] = F;
        }
    }
}

// ---------------- tail: combine partials + scalar math + dedup scatter -----
__global__ __launch_bounds__(256) void tail_kernel(
        const float* __restrict__ partials,
        const int* __restrict__ image_ids, const int* __restrict__ text_ids,
        const float* __restrict__ b_I, const float* __restrict__ b_T,
        const float* __restrict__ s_I, const float* __restrict__ s_T,
        const float* __restrict__ u_I, const float* __restrict__ u_T,
        const float* __restrict__ tau_row, const int* __restrict__ epoch_ptr,
        float* __restrict__ loss_arr, float* __restrict__ out) {
    __shared__ int sids[BDIM];
    const int bx = blockIdx.x;
    const int p = bx >> 10;
    const int* ids = p ? text_ids : image_ids;
    for (int i = threadIdx.x; i < BDIM / 4; i += 256)
        ((int4*)sids)[i] = ((const int4*)ids)[i];

    const int wave = threadIdx.x >> 6, lane = threadIdx.x & 63;
    const int row = (bx & 1023) * 4 + wave;
    float m, E, F;
    if (p == 1 && lane >= 32) {
        m = -3.0e38f; E = 0.f; F = 0.f;
    } else {
        const float* pp = partials + (((size_t)p * BDIM + row) * 64 + lane) * 3;
        m = pp[0]; E = pp[1]; F = pp[2];
    }
    #pragma unroll
    for (int d = 1; d < 64; d <<= 1) {
        float mo = __shfl_xor(m, d), Eo = __shfl_xor(E, d), Fo = __shfl_xor(F, d);
        float mn = fmaxf(m, mo);
        float a1 = expf(m - mn), a2 = expf(mo - mn);
        E = E * a1 + Eo * a2;
        F = F * a1 + Fo * a2;
        m = mn;
    }
    const int id = ids[row];
    const float ob = p ? b_T[id] : b_I[id];
    const float so = p ? s_T[id] : s_I[id];
    const float uo = p ? u_T[id] : u_I[id];
    const float tv = tau_row[p * BDIM + row];
    const float m0 = fmaxf(ob, 0.0f);      // reference max includes idt[i,i]=0 and old_b
    if (m0 > m) { float sc = expf(m - m0); E *= sc; F *= sc; m = m0; }
    float sI = (*epoch_ptr == 0) ? E : 0.2f * so * expf(ob - m) + 0.8f * E;
    float sc_ = fmaxf(sI, 1e-14f);
    float ratio = F / sc_;
    float twi = logf(sc_ * (1.0f / 4095.0f)) + m + 8.0f - ratio;
    float uc = fminf(fmaxf(twi, -5.0f), 5.0f);
    float ub = 0.5f * uo + 0.5f * uc;
    float tb = fminf(fmaxf(tv - 0.03f * ub, 0.005f), 0.05f);
    if (lane == 0) loss_arr[p * BDIM + row] = tv * ratio;

    __syncthreads();                        // sids staged
    const int myid = sids[row];
    bool dup = false;
    for (int c = row + 1 + lane; c < BDIM; c += 64)
        dup |= (sids[c] == myid);
    if (__any(dup)) return;                 // a later duplicate wins
    if (lane < 4) {
        const float v = (lane == 0) ? m : (lane == 1) ? sI : (lane == 2) ? ub : tb;
        const int arr = (lane == 0) ? (2 + p) : (lane == 1) ? (0 + p)
                      : (lane == 2) ? (4 + p) : (6 + p);
        out[8193 + (size_t)arr * N_ITEMS + myid] = v;
    }
}

// ---------------- deterministic loss reduction -----------------------------
__global__ void loss_kernel(const float* __restrict__ loss_arr, float* __restrict__ out) {
    __shared__ float wsum[16];
    int t = threadIdx.x;
    float s = 0.f;
    for (int i = t; i < 2 * BDIM; i += 1024) s += loss_arr[i];
    #pragma unroll
    for (int d = 32; d >= 1; d >>= 1) s += __shfl_xor(s, d);
    if ((t & 63) == 0) wsum[t >> 6] = s;
    __syncthreads();
    if (t == 0) {
        float tot = 0.f;
        for (int i = 0; i < 16; i++) tot += wsum[i];
        out[0] = tot * (1.0f / (float)BDIM);  // mean(img)+mean(txt) = sum(all)/B
    }
}

extern "C" void kernel_launch(void* const* d_in, const int* in_sizes, int n_in,
                              void* d_out, int out_size, void* d_ws, size_t ws_size,
                              hipStream_t stream) {
    const float* img       = (const float*)d_in[0];
    const float* txt       = (const float*)d_in[1];
    const int*   image_ids = (const int*)d_in[2];
    const int*   text_ids  = (const int*)d_in[3];
    const int*   epoch     = (const int*)d_in[4];
    const float* s_I   = (const float*)d_in[6];
    const float* s_T   = (const float*)d_in[7];
    const float* b_I   = (const float*)d_in[8];
    const float* b_T   = (const float*)d_in[9];
    const float* u_I   = (const float*)d_in[10];
    const float* u_T   = (const float*)d_in[11];
    const float* tau_I = (const float*)d_in[12];
    const float* tau_T = (const float*)d_in[13];
    float* out = (float*)d_out;

    char* ws = (char*)d_ws;
    unsigned short* Xbf = (unsigned short*)ws;                    // 6,291,456 B
    unsigned short* Ybf = (unsigned short*)(ws + 6291456);        // 6,291,456 B
    float* diag     = (float*)(ws + 12582912);                    // 16 KB
    float* tau_row  = (float*)(ws + 12599296);                    // 32 KB
    float* partials = (float*)(ws + 12632064);                    // 6,291,456 B
    float* loss_arr = (float*)(ws + 18923520);                    // 32 KB
    float* dump     = (float*)(ws + 18956288);                    // 2 KB scratch

    prep_kernel<<<1024, 256, 0, stream>>>(img, txt, image_ids, text_ids, tau_I, tau_T,
                                          Xbf, Ybf, diag, tau_row, out);
    gemm_kernel<<<dim3(16, 16), 512, 0, stream>>>(Xbf, Ybf, diag, tau_row, partials,
                                                  s_I, s_T, b_I, b_T, u_I, u_T,
                                                  tau_I, tau_T, out + 8193, dump);
    tail_kernel<<<2048, 256, 0, stream>>>(partials, image_ids, text_ids,
                                          b_I, b_T, s_I, s_T, u_I, u_T,
                                          tau_row, epoch, loss_arr, out);
    loss_kernel<<<1, 1024, 0, stream>>>(loss_arr, out);
}